// Round 1
// baseline (469.182 us; speedup 1.0000x reference)
//
#include <hip/hip_runtime.h>

// Adaptive_Node_Scale_GCN: B=16, C=16, D=4, K=128, L=128, E=10
// Y[d,n] = sum_{t=0..6} W_t,d * X[d,n] * M_{t,d}^T
// mats in ws: 12 matrices, stored transposed MT[v][k] = M[k][v], fp32:
//   0: A0^T, 1: (A0^2)^T, 2: A1^T, 3: (A1^2)^T, 4+2d: P_d^T, 5+2d: (P_d^2)^T

namespace {

constexpr int Kn = 128;
constexpr int En = 10;

__global__ __launch_bounds__(256) void build_adj(
    const float* __restrict__ supports,
    const float* __restrict__ nv1,
    const float* __restrict__ nv2,
    const float* __restrict__ impW,
    const float* __restrict__ impB,
    float* __restrict__ mats)
{
    const int tid = threadIdx.x;
    const int blk = blockIdx.x;
    if (blk < 2) {
        // transpose-copy A_s -> mats[2*blk]  (scattered L2 reads, coalesced writes)
        const float* A = supports + blk * Kn * Kn;
        float* dst = mats + (2 * blk) * Kn * Kn;
        for (int i = tid; i < Kn * Kn; i += 256) {
            const int v = i >> 7, k = i & 127;
            dst[i] = A[k * Kn + v];
        }
        return;
    }
    const int d = blk - 2;
    __shared__ float nv1m[Kn * En];
    __shared__ float nv2s[En * Kn];
    for (int i = tid; i < Kn * En; i += 256) nv1m[i] = nv1[d * Kn * En + i];
    for (int i = tid; i < En * Kn; i += 256) nv2s[i] = nv2[d * En * Kn + i];
    __syncthreads();
    // imp[j,e] = sum_k impW[j,k] * nv1[k,e] + impB[j]   (1280 entries, 5/thread)
    float impv[5];
    #pragma unroll
    for (int r = 0; r < 5; ++r) {
        const int idx = tid + r * 256;
        const int j = idx / En, e = idx - j * En;
        float acc = impB[j];
        for (int kk = 0; kk < Kn; ++kk)
            acc += impW[j * Kn + kk] * nv1m[kk * En + e];
        impv[r] = acc;
    }
    __syncthreads();
    #pragma unroll
    for (int r = 0; r < 5; ++r) nv1m[tid + r * 256] *= impv[r];
    __syncthreads();
    // scores[k,j] = sum_e nv1m[k,e]*nv2[e,j]; relu; softmax over j; write P^T
    if (tid < Kn) {
        const int k = tid;
        float a[En];
        #pragma unroll
        for (int e = 0; e < En; ++e) a[e] = nv1m[k * En + e];
        float mx = 0.f;  // relu floor
        for (int j = 0; j < Kn; ++j) {
            float s = 0.f;
            #pragma unroll
            for (int e = 0; e < En; ++e) s += a[e] * nv2s[e * Kn + j];
            mx = fmaxf(mx, s);
        }
        float sum = 0.f;
        for (int j = 0; j < Kn; ++j) {
            float s = 0.f;
            #pragma unroll
            for (int e = 0; e < En; ++e) s += a[e] * nv2s[e * Kn + j];
            s = fmaxf(s, 0.f);
            sum += expf(s - mx);
        }
        const float inv = 1.f / sum;
        float* dst = mats + (4 + 2 * d) * Kn * Kn;
        for (int j = 0; j < Kn; ++j) {
            float s = 0.f;
            #pragma unroll
            for (int e = 0; e < En; ++e) s += a[e] * nv2s[e * Kn + j];
            s = fmaxf(s, 0.f);
            dst[j * Kn + k] = expf(s - mx) * inv;  // P^T[j][k] = P[k][j]
        }
    }
}

// (M^2)^T[v][k] = sum_u MT[u][k] * MT[v][u]  -- staging is a straight copy
__global__ __launch_bounds__(256) void square_adj(float* __restrict__ mats)
{
    __shared__ float S[Kn * Kn];
    const int tid = threadIdx.x;
    const float* src = mats + (2 * blockIdx.x) * Kn * Kn;
    float* dst = mats + (2 * blockIdx.x + 1) * Kn * Kn;
    for (int i = tid; i < Kn * Kn; i += 256) S[i] = src[i];
    __syncthreads();
    for (int i = tid; i < Kn * Kn; i += 256) {
        const int v = i >> 7, k = i & 127;
        float acc = 0.f;
        for (int u = 0; u < Kn; ++u)
            acc += S[u * Kn + k] * S[v * Kn + u];
        dst[i] = acc;
    }
}

// block = (d, b, 8-l tile). LDS X tile [c][l][v] with XOR swizzle col = v ^ (l<<2).
__global__ __launch_bounds__(256) void fused_main(
    const float* __restrict__ x,
    const float* __restrict__ mats,
    const float* __restrict__ mlpW,   // (4,16,112)
    const float* __restrict__ mlpB,   // (4,16)
    float* __restrict__ out)
{
    __shared__ float Xs[16 * 8 * 128];  // 64 KB exactly
    const int tid = threadIdx.x;

    // XCD-chunked swizzle: sibling l-tiles (sharing 64B lines) land on same XCD
    const unsigned u = blockIdx.x;            // 0..1023
    const unsigned xcd = u & 7, w = u >> 3;   // w: 0..127
    const unsigned sib = w & 1;
    const unsigned pid = xcd * 64 + (w >> 1); // 0..511
    const int d  = pid >> 7;
    const int b  = (pid >> 3) & 15;
    const int lt = (int)(((pid & 7) << 1) | sib);
    const int l0 = lt * 8;

    // stage X[c][l][v] = x[b,c,d,v,l0+l]
    const float* xb = x + b * 1048576 + d * 16384 + l0;
    for (int j = tid; j < 4096; j += 256) {
        const int c = j >> 8, v = (j >> 1) & 127, half = j & 1;
        const float4 f4 = *reinterpret_cast<const float4*>(xb + c * 65536 + v * 128 + half * 4);
        const int l0q = half * 4;
        Xs[(c * 8 + l0q + 0) * 128 + (v ^ ((l0q + 0) << 2))] = f4.x;
        Xs[(c * 8 + l0q + 1) * 128 + (v ^ ((l0q + 1) << 2))] = f4.y;
        Xs[(c * 8 + l0q + 2) * 128 + (v ^ ((l0q + 2) << 2))] = f4.z;
        Xs[(c * 8 + l0q + 3) * 128 + (v ^ ((l0q + 3) << 2))] = f4.w;
    }
    __syncthreads();

    const int k0 = (tid & 31) * 4;   // 4 contiguous k per thread
    const int lp = tid >> 5;         // 1 l per thread (0..7)
    const int xorv = lp << 2;
    const float* Wd = mlpW + d * 1792;

    float y[16][4], z[16][4];
    #pragma unroll
    for (int o = 0; o < 16; ++o)
        #pragma unroll
        for (int i = 0; i < 4; ++i) y[o][i] = 0.f;

    // t = 0 : identity term
    #pragma unroll
    for (int c = 0; c < 16; ++c) {
        const float4 q = *reinterpret_cast<const float4*>(&Xs[(c * 8 + lp) * 128 + (k0 ^ xorv)]);
        z[c][0] = q.x; z[c][1] = q.y; z[c][2] = q.z; z[c][3] = q.w;
    }
    #pragma unroll
    for (int o = 0; o < 16; ++o) {
        #pragma unroll
        for (int c = 0; c < 16; ++c) {
            const float wv = Wd[o * 112 + c];
            #pragma unroll
            for (int i = 0; i < 4; ++i) y[o][i] += wv * z[c][i];
        }
    }

    #pragma unroll 1
    for (int t = 1; t <= 6; ++t) {
        const int m_idx = (t <= 4) ? (t - 1) : (4 + 2 * d + (t - 5));
        const float* MT = mats + m_idx * 16384 + k0;
        #pragma unroll
        for (int c = 0; c < 16; ++c)
            #pragma unroll
            for (int i = 0; i < 4; ++i) z[c][i] = 0.f;

        for (int v4 = 0; v4 < 128; v4 += 4) {
            const float4 m0 = *reinterpret_cast<const float4*>(MT + (v4 + 0) * 128);
            const float4 m1 = *reinterpret_cast<const float4*>(MT + (v4 + 1) * 128);
            const float4 m2 = *reinterpret_cast<const float4*>(MT + (v4 + 2) * 128);
            const float4 m3 = *reinterpret_cast<const float4*>(MT + (v4 + 3) * 128);
            #pragma unroll
            for (int c = 0; c < 16; ++c) {
                const float4 xq = *reinterpret_cast<const float4*>(&Xs[(c * 8 + lp) * 128 + (v4 ^ xorv)]);
                z[c][0] += m0.x * xq.x; z[c][0] += m1.x * xq.y; z[c][0] += m2.x * xq.z; z[c][0] += m3.x * xq.w;
                z[c][1] += m0.y * xq.x; z[c][1] += m1.y * xq.y; z[c][1] += m2.y * xq.z; z[c][1] += m3.y * xq.w;
                z[c][2] += m0.z * xq.x; z[c][2] += m1.z * xq.y; z[c][2] += m2.z * xq.z; z[c][2] += m3.z * xq.w;
                z[c][3] += m0.w * xq.x; z[c][3] += m1.w * xq.y; z[c][3] += m2.w * xq.z; z[c][3] += m3.w * xq.w;
            }
        }
        #pragma unroll
        for (int o = 0; o < 16; ++o) {
            #pragma unroll
            for (int c = 0; c < 16; ++c) {
                const float wv = Wd[o * 112 + t * 16 + c];
                #pragma unroll
                for (int i = 0; i < 4; ++i) y[o][i] += wv * z[c][i];
            }
        }
    }

    // out[b, o, d, k, l] = y + bias
    float* ob = out + b * 1048576 + d * 16384 + l0 + lp;
    #pragma unroll
    for (int o = 0; o < 16; ++o) {
        const float bias = mlpB[d * 16 + o];
        #pragma unroll
        for (int i = 0; i < 4; ++i)
            ob[o * 65536 + (k0 + i) * 128] = y[o][i] + bias;
    }
}

}  // namespace

extern "C" void kernel_launch(void* const* d_in, const int* in_sizes, int n_in,
                              void* d_out, int out_size, void* d_ws, size_t ws_size,
                              hipStream_t stream)
{
    const float* x    = (const float*)d_in[0];
    const float* sup  = (const float*)d_in[1];
    const float* nv1  = (const float*)d_in[2];
    const float* nv2  = (const float*)d_in[3];
    const float* impW = (const float*)d_in[4];
    const float* impB = (const float*)d_in[5];
    const float* mlpW = (const float*)d_in[6];
    const float* mlpB = (const float*)d_in[7];
    float* outp = (float*)d_out;
    float* mats = (float*)d_ws;   // 12 * 128 * 128 * 4 B = 768 KB

    build_adj<<<6, 256, 0, stream>>>(sup, nv1, nv2, impW, impB, mats);
    square_adj<<<6, 256, 0, stream>>>(mats);
    fused_main<<<1024, 256, 0, stream>>>(x, mats, mlpW, mlpB, outp);
}

// Round 2
// 214.710 us; speedup vs baseline: 2.1852x; 2.1852x over previous
//
#include <hip/hip_runtime.h>

// Adaptive_Node_Scale_GCN — MFMA version.
// Y[d,n] = sum_{t=0..6} W_t,d · X_{d,n} · M_{t,d}^T,  M ∈ {I, A0, A0², A1, A1², P_d, P_d²}
// ws: fp32 mats (12 × 64KB) then bf16 stream mats (13 × 32KB), bf16 stored row-major
// M[k][v] with byte-level XOR swizzle (v ^= (k&7)<<3 at element level) so the fused
// kernel can copy linearly into LDS and read conflict-free B-fragments.

namespace {

constexpr int Kn = 128;
constexpr int En = 10;

typedef __attribute__((ext_vector_type(8))) short short8;
typedef __attribute__((ext_vector_type(4))) float f32x4;

__device__ inline unsigned short f2bf(float f) {
    unsigned x = __float_as_uint(f);
    return (unsigned short)((x + 0x7FFFu + ((x >> 16) & 1u)) >> 16);
}

// ---------------- precompute: fp32 mats, row-major M[k][v] ----------------
// fp32 slots: 0:A0 1:A0² 2:A1 3:A1² 4..7:P_d 8..11:P²_d
__global__ __launch_bounds__(256) void build_adj(
    const float* __restrict__ supports,
    const float* __restrict__ nv1,
    const float* __restrict__ nv2,
    const float* __restrict__ impW,
    const float* __restrict__ impB,
    float* __restrict__ mats)
{
    const int tid = threadIdx.x;
    const int blk = blockIdx.x;
    if (blk < 2) {
        const float* A = supports + blk * Kn * Kn;
        float* dst = mats + (blk * 2) * Kn * Kn;   // slot 0 / slot 2
        for (int i = tid; i < Kn * Kn; i += 256) dst[i] = A[i];
        return;
    }
    const int d = blk - 2;
    __shared__ float nv1m[Kn * En];
    __shared__ float nv2s[En * Kn];
    for (int i = tid; i < Kn * En; i += 256) nv1m[i] = nv1[d * Kn * En + i];
    for (int i = tid; i < En * Kn; i += 256) nv2s[i] = nv2[d * En * Kn + i];
    __syncthreads();
    float impv[5];
    #pragma unroll
    for (int r = 0; r < 5; ++r) {
        const int idx = tid + r * 256;
        const int j = idx / En, e = idx - j * En;
        float acc = impB[j];
        for (int kk = 0; kk < Kn; ++kk)
            acc += impW[j * Kn + kk] * nv1m[kk * En + e];
        impv[r] = acc;
    }
    __syncthreads();
    #pragma unroll
    for (int r = 0; r < 5; ++r) nv1m[tid + r * 256] *= impv[r];
    __syncthreads();
    if (tid < Kn) {
        const int k = tid;
        float a[En];
        #pragma unroll
        for (int e = 0; e < En; ++e) a[e] = nv1m[k * En + e];
        float mx = 0.f;
        for (int j = 0; j < Kn; ++j) {
            float s = 0.f;
            #pragma unroll
            for (int e = 0; e < En; ++e) s += a[e] * nv2s[e * Kn + j];
            mx = fmaxf(mx, s);
        }
        float sum = 0.f;
        for (int j = 0; j < Kn; ++j) {
            float s = 0.f;
            #pragma unroll
            for (int e = 0; e < En; ++e) s += a[e] * nv2s[e * Kn + j];
            s = fmaxf(s, 0.f);
            sum += expf(s - mx);
        }
        const float inv = 1.f / sum;
        float* dst = mats + (4 + d) * Kn * Kn;
        for (int j = 0; j < Kn; ++j) {
            float s = 0.f;
            #pragma unroll
            for (int e = 0; e < En; ++e) s += a[e] * nv2s[e * Kn + j];
            s = fmaxf(s, 0.f);
            dst[k * Kn + j] = expf(s - mx) * inv;   // P[k][j], row-major
        }
    }
}

// M²[k][v] = sum_u M[k][u] M[u][v]
__global__ __launch_bounds__(256) void square_adj(float* __restrict__ mats)
{
    __shared__ float S[Kn * Kn];
    const int tid = threadIdx.x;
    const int bi = blockIdx.x;
    const int src = (bi == 0) ? 0 : (bi == 1) ? 2 : (2 + bi);   // 4..7
    const int dst = (bi == 0) ? 1 : (bi == 1) ? 3 : (6 + bi);   // 8..11
    const float* s = mats + src * Kn * Kn;
    float* o = mats + dst * Kn * Kn;
    for (int i = tid; i < Kn * Kn; i += 256) S[i] = s[i];
    __syncthreads();
    for (int i = tid; i < Kn * Kn; i += 256) {
        const int k = i >> 7, v = i & 127;
        float acc = 0.f;
        for (int u = 0; u < Kn; ++u)
            acc += S[k * 128 + u] * S[u * 128 + v];
        o[i] = acc;
    }
}

// bf16 stream slots: 0:I 1:A0 2:A0² 3:A1 4:A1² 5+2d:P_d 6+2d:P²_d  (pre-swizzled)
__global__ __launch_bounds__(256) void cvt_mats(
    const float* __restrict__ fm, unsigned short* __restrict__ wbm)
{
    const int s = blockIdx.x;
    const int src = (s == 0) ? -1
                  : (s < 5)  ? (s - 1)
                  : (((s - 5) & 1) ? (8 + ((s - 5) >> 1)) : (4 + ((s - 5) >> 1)));
    for (int i = threadIdx.x; i < 16384; i += 256) {
        const int k = i >> 7, col = i & 127;
        const int v = col ^ ((k & 7) << 3);
        const float val = (src < 0) ? ((k == v) ? 1.f : 0.f)
                                    : fm[src * 16384 + k * 128 + v];
        wbm[s * 16384 + i] = f2bf(val);
    }
}

// ---------------- fused MFMA kernel ----------------
// block = (d, b, 8 l's). LDS: Xa [0,32K) rows=(n*16+c)×v bf16 swz; Mbuf [32K,48K);
// Z [48K,80K) = [n][k'][tp][c] bf16 swz.
__global__ __launch_bounds__(256, 2) void fused_mfma(
    const float* __restrict__ x,
    const unsigned short* __restrict__ wbm,
    const float* __restrict__ mlpW,   // (4,16,112)
    const float* __restrict__ mlpB,   // (4,16)
    float* __restrict__ out)
{
    __shared__ __align__(16) char lds[81920];
    const int tid = threadIdx.x;
    const int lane = tid & 63, lr = lane & 15, lg = lane >> 4;
    const int wid = tid >> 6, wr = wid >> 1, wk = wid & 1;

    const unsigned u = blockIdx.x;                 // 0..1023
    const unsigned pid = (u & 7) * 128 + (u >> 3); // XCD-chunked
    const int d = pid >> 8, b = (pid >> 4) & 15, lt = pid & 15;
    const int l0 = lt * 8;

    // ---- stage X -> Xa[(n*16+c)][v] bf16, swizzled: byte = row*256 + (2v ^ ((row&7)<<4))
    {
        const int c = tid >> 4, vi = tid & 15;
        const float* xb = x + (size_t)b * 1048576 + d * 16384 + l0 + c * 65536;
        const int swz = (c & 7) << 4;
        #pragma unroll
        for (int vp = 0; vp < 4; ++vp) {
            const int v = (vp * 16 + vi) * 2;
            const float* p0 = xb + v * 128;
            const float4 a0 = *reinterpret_cast<const float4*>(p0);
            const float4 a1 = *reinterpret_cast<const float4*>(p0 + 4);
            const float4 b0 = *reinterpret_cast<const float4*>(p0 + 128);
            const float4 b1 = *reinterpret_cast<const float4*>(p0 + 132);
            const float av[8] = {a0.x, a0.y, a0.z, a0.w, a1.x, a1.y, a1.z, a1.w};
            const float bv[8] = {b0.x, b0.y, b0.z, b0.w, b1.x, b1.y, b1.z, b1.w};
            #pragma unroll
            for (int n = 0; n < 8; ++n) {
                const unsigned pk = (unsigned)f2bf(av[n]) | ((unsigned)f2bf(bv[n]) << 16);
                *reinterpret_cast<unsigned*>(lds + (n * 16 + c) * 256 + ((v * 2) ^ swz)) = pk;
            }
        }
    }

    // ---- W fragments (A-operand of phase B), zero-padded 8th t-slot
    short8 Wf[4];
    #pragma unroll
    for (int p = 0; p < 4; ++p) {
        short8 w;
        #pragma unroll
        for (int j = 0; j < 8; ++j) {
            const int tc = lg * 8 + j, t = 2 * p + (tc >> 4), c = tc & 15;
            const float wv = (t < 7) ? mlpW[d * 1792 + lr * 112 + t * 16 + c] : 0.f;
            w[j] = (short)f2bf(wv);
        }
        Wf[p] = w;
    }

    __syncthreads();

    // ---- X A-fragments -> registers (reused across all t)
    short8 Xf[4][4];
    {
        const int swz = (lr & 7) << 4;
        #pragma unroll
        for (int rti = 0; rti < 4; ++rti) {
            const int base = ((wr * 4 + rti) * 16 + lr) * 256;
            #pragma unroll
            for (int ks = 0; ks < 4; ++ks)
                Xf[rti][ks] = *reinterpret_cast<const short8*>(
                    lds + base + ((ks * 64 + lg * 16) ^ swz));
        }
    }

    const f32x4 zero4 = {0.f, 0.f, 0.f, 0.f};
    f32x4 Y[2][8];
    #pragma unroll
    for (int ni = 0; ni < 2; ++ni)
        #pragma unroll
        for (int kt = 0; kt < 8; ++kt) Y[ni][kt] = zero4;

    #pragma unroll
    for (int p = 0; p < 4; ++p) {
        #pragma unroll
        for (int kh = 0; kh < 2; ++kh) {
            #pragma unroll
            for (int tp = 0; tp < ((p == 3) ? 1 : 2); ++tp) {
                const int tpos = 2 * p + tp;
                const int slot = (tpos < 5) ? tpos : (5 + 2 * d + (tpos - 5));
                // stage M[slot] rows kh*64..kh*64+63 -> Mbuf (linear copy; pre-swizzled)
                {
                    const unsigned short* src = wbm + slot * 16384 + kh * 8192;
                    #pragma unroll
                    for (int i = 0; i < 4; ++i) {
                        const int off = tid * 8 + i * 2048;
                        *reinterpret_cast<short8*>(lds + 32768 + off * 2) =
                            *reinterpret_cast<const short8*>(src + off);
                    }
                }
                __syncthreads();
                // phase A: Z = X · M^T for this (t, k-half)
                f32x4 D[4][2];
                #pragma unroll
                for (int rti = 0; rti < 4; ++rti)
                    #pragma unroll
                    for (int j = 0; j < 2; ++j) D[rti][j] = zero4;
                #pragma unroll
                for (int ks = 0; ks < 4; ++ks) {
                    short8 Bf[2];
                    #pragma unroll
                    for (int j = 0; j < 2; ++j) {
                        const int kp = (wk * 2 + j) * 16 + lr;
                        Bf[j] = *reinterpret_cast<const short8*>(
                            lds + 32768 + kp * 256 + ((ks * 64 + lg * 16) ^ ((kp & 7) << 4)));
                    }
                    #pragma unroll
                    for (int rti = 0; rti < 4; ++rti)
                        #pragma unroll
                        for (int j = 0; j < 2; ++j)
                            D[rti][j] = __builtin_amdgcn_mfma_f32_16x16x32_bf16(
                                Xf[rti][ks], Bf[j], D[rti][j], 0, 0, 0);
                }
                // write Z[n][k'][tp][c] bf16 (rows of D are c; cols are k')
                #pragma unroll
                for (int rti = 0; rti < 4; ++rti) {
                    #pragma unroll
                    for (int j = 0; j < 2; ++j) {
                        const int n = wr * 4 + rti;
                        const int kp = (wk * 2 + j) * 16 + lr;
                        const unsigned u0 =
                            (unsigned)f2bf(D[rti][j][0]) | ((unsigned)f2bf(D[rti][j][1]) << 16);
                        const unsigned u1 =
                            (unsigned)f2bf(D[rti][j][2]) | ((unsigned)f2bf(D[rti][j][3]) << 16);
                        char* zp = lds + 49152 + n * 4096 +
                                   ((kp * 64 + tp * 32 + lg * 8) ^ ((kp & 7) << 4));
                        *reinterpret_cast<unsigned*>(zp) = u0;
                        *reinterpret_cast<unsigned*>(zp + 4) = u1;
                    }
                }
                __syncthreads();
            }
            // phase B: Y += W_pair · Z
            #pragma unroll
            for (int ni = 0; ni < 2; ++ni) {
                #pragma unroll
                for (int ktl = 0; ktl < 4; ++ktl) {
                    const int n = wid * 2 + ni;
                    const int kp = ktl * 16 + lr;
                    const short8 Bf = *reinterpret_cast<const short8*>(
                        lds + 49152 + n * 4096 + ((kp * 64 + lg * 16) ^ ((kp & 7) << 4)));
                    Y[ni][kh * 4 + ktl] = __builtin_amdgcn_mfma_f32_16x16x32_bf16(
                        Wf[p], Bf, Y[ni][kh * 4 + ktl], 0, 0, 0);
                }
            }
            __syncthreads();
        }
    }

    // ---- store: out[b, o, d, k, l0+n], D rows are o = 4*lg + r
    f32x4 bias;
    #pragma unroll
    for (int r = 0; r < 4; ++r) bias[r] = mlpB[d * 16 + lg * 4 + r];
    float* ob = out + (size_t)b * 1048576 + d * 16384 + l0;
    #pragma unroll
    for (int ni = 0; ni < 2; ++ni) {
        const int n = wid * 2 + ni;
        #pragma unroll
        for (int kt = 0; kt < 8; ++kt) {
            float* pp = ob + (kt * 16 + lr) * 128 + n;
            #pragma unroll
            for (int r = 0; r < 4; ++r)
                pp[(lg * 4 + r) * 65536] = Y[ni][kt][r] + bias[r];
        }
    }
}

}  // namespace

extern "C" void kernel_launch(void* const* d_in, const int* in_sizes, int n_in,
                              void* d_out, int out_size, void* d_ws, size_t ws_size,
                              hipStream_t stream)
{
    const float* x    = (const float*)d_in[0];
    const float* sup  = (const float*)d_in[1];
    const float* nv1  = (const float*)d_in[2];
    const float* nv2  = (const float*)d_in[3];
    const float* impW = (const float*)d_in[4];
    const float* impB = (const float*)d_in[5];
    const float* mlpW = (const float*)d_in[6];
    const float* mlpB = (const float*)d_in[7];
    float* outp = (float*)d_out;

    float* fm = (float*)d_ws;                                        // 12 × 64KB fp32
    unsigned short* wbm = (unsigned short*)((char*)d_ws + 786432);   // 13 × 32KB bf16

    build_adj<<<6, 256, 0, stream>>>(sup, nv1, nv2, impW, impB, fm);
    square_adj<<<6, 256, 0, stream>>>(fm);
    cvt_mats<<<13, 256, 0, stream>>>(fm, wbm);
    fused_mfma<<<1024, 256, 0, stream>>>(x, wbm, mlpW, mlpB, outp);
}

// Round 3
// 161.420 us; speedup vs baseline: 2.9066x; 1.3301x over previous
//
#include <hip/hip_runtime.h>

// Adaptive_Node_Scale_GCN — MFMA v2 (overlaid Z, kh-in-grid, M reg-prefetch).
// Y[d,n] = sum_{t=0..6} W_t,d · X_{d,n} · M_{t,d}^T,  M ∈ {I, A0, A0², A1, A1², P_d, P_d²}
// ws: fp32 mats (12 × 64KB) then bf16 stream mats (13 × 32KB), row-major M[k][v]
// with element-level XOR swizzle (v ^= (k&7)<<3) so LDS staging is a linear copy
// and B-fragment ds_read_b128 is conflict-free.

namespace {

constexpr int Kn = 128;
constexpr int En = 10;

typedef __attribute__((ext_vector_type(8))) short short8;
typedef __attribute__((ext_vector_type(4))) float f32x4;

__device__ inline unsigned short f2bf(float f) {
    unsigned x = __float_as_uint(f);
    return (unsigned short)((x + 0x7FFFu + ((x >> 16) & 1u)) >> 16);
}

// ---------------- precompute: fp32 mats, row-major M[k][v] ----------------
// fp32 slots: 0:A0 1:A0² 2:A1 3:A1² 4..7:P_d 8..11:P²_d
__global__ __launch_bounds__(256) void build_adj(
    const float* __restrict__ supports,
    const float* __restrict__ nv1,
    const float* __restrict__ nv2,
    const float* __restrict__ impW,
    const float* __restrict__ impB,
    float* __restrict__ mats)
{
    const int tid = threadIdx.x;
    const int blk = blockIdx.x;
    if (blk < 2) {
        const float* A = supports + blk * Kn * Kn;
        float* dst = mats + (blk * 2) * Kn * Kn;   // slot 0 / slot 2
        for (int i = tid; i < Kn * Kn; i += 256) dst[i] = A[i];
        return;
    }
    const int d = blk - 2;
    __shared__ float nv1m[Kn * En];
    __shared__ float nv2s[En * Kn];
    for (int i = tid; i < Kn * En; i += 256) nv1m[i] = nv1[d * Kn * En + i];
    for (int i = tid; i < En * Kn; i += 256) nv2s[i] = nv2[d * En * Kn + i];
    __syncthreads();
    float impv[5];
    #pragma unroll
    for (int r = 0; r < 5; ++r) {
        const int idx = tid + r * 256;
        const int j = idx / En, e = idx - j * En;
        float acc = impB[j];
        for (int kk = 0; kk < Kn; ++kk)
            acc += impW[j * Kn + kk] * nv1m[kk * En + e];
        impv[r] = acc;
    }
    __syncthreads();
    #pragma unroll
    for (int r = 0; r < 5; ++r) nv1m[tid + r * 256] *= impv[r];
    __syncthreads();
    if (tid < Kn) {
        const int k = tid;
        float a[En];
        #pragma unroll
        for (int e = 0; e < En; ++e) a[e] = nv1m[k * En + e];
        float mx = 0.f;
        for (int j = 0; j < Kn; ++j) {
            float s = 0.f;
            #pragma unroll
            for (int e = 0; e < En; ++e) s += a[e] * nv2s[e * Kn + j];
            mx = fmaxf(mx, s);
        }
        float sum = 0.f;
        for (int j = 0; j < Kn; ++j) {
            float s = 0.f;
            #pragma unroll
            for (int e = 0; e < En; ++e) s += a[e] * nv2s[e * Kn + j];
            s = fmaxf(s, 0.f);
            sum += expf(s - mx);
        }
        const float inv = 1.f / sum;
        float* dst = mats + (4 + d) * Kn * Kn;
        for (int j = 0; j < Kn; ++j) {
            float s = 0.f;
            #pragma unroll
            for (int e = 0; e < En; ++e) s += a[e] * nv2s[e * Kn + j];
            s = fmaxf(s, 0.f);
            dst[k * Kn + j] = expf(s - mx) * inv;   // P[k][j], row-major
        }
    }
}

// M²[k][v] = sum_u M[k][u] M[u][v]; 96 blocks: 6 mats × 16 strips of 8 rows
__global__ __launch_bounds__(256) void square_adj(float* __restrict__ mats)
{
    __shared__ float S[Kn * Kn];
    const int tid = threadIdx.x;
    const int m = blockIdx.x >> 4, strip = blockIdx.x & 15;
    const int src = (m == 0) ? 0 : (m == 1) ? 2 : (2 + m);   // 4..7
    const int dst = (m == 0) ? 1 : (m == 1) ? 3 : (6 + m);   // 8..11
    const float* s = mats + src * Kn * Kn;
    float* o = mats + dst * Kn * Kn;
    for (int i = tid; i < Kn * Kn; i += 256)
        S[i] = s[i];
    __syncthreads();
    const int v = strip * 8 + (tid >> 5);
    const int k0 = (tid & 31) * 4;
    float acc0 = 0.f, acc1 = 0.f, acc2 = 0.f, acc3 = 0.f;
    for (int u0 = 0; u0 < Kn; u0 += 4) {
        const float4 av = *reinterpret_cast<const float4*>(&S[v * Kn + u0]);
        const float a[4] = {av.x, av.y, av.z, av.w};
        #pragma unroll
        for (int j = 0; j < 4; ++j) {
            const float4 m4 = *reinterpret_cast<const float4*>(&S[(u0 + j) * Kn + k0]);
            acc0 += a[j] * m4.x; acc1 += a[j] * m4.y;
            acc2 += a[j] * m4.z; acc3 += a[j] * m4.w;
        }
    }
    float4 r = {acc0, acc1, acc2, acc3};
    *reinterpret_cast<float4*>(&o[v * Kn + k0]) = r;
}

// bf16 stream slots: 0:I 1:A0 2:A0² 3:A1 4:A1² 5+2d:P_d 6+2d:P²_d  (pre-swizzled)
__global__ __launch_bounds__(256) void cvt_mats(
    const float* __restrict__ fm, unsigned short* __restrict__ wbm)
{
    const int s = blockIdx.x;
    const int src = (s == 0) ? -1
                  : (s < 5)  ? (s - 1)
                  : (((s - 5) & 1) ? (8 + ((s - 5) >> 1)) : (4 + ((s - 5) >> 1)));
    for (int i = threadIdx.x; i < 16384; i += 256) {
        const int k = i >> 7, col = i & 127;
        const int v = col ^ ((k & 7) << 3);
        const float val = (src < 0) ? ((k == v) ? 1.f : 0.f)
                                    : fm[src * 16384 + k * 128 + v];
        wbm[s * 16384 + i] = f2bf(val);
    }
}

// ---------------- fused MFMA kernel ----------------
// block = (d, b, 8 l's, k-half). LDS 48KB:
//   [0,32K): Xa (prologue only) then Z overlay  [n][kp 64][tp 2][c 16] bf16 swz
//   [32K,48K): Mbuf — one 64-row half-slab of M, pre-swizzled
__global__ __launch_bounds__(256, 3) void fused_mfma(
    const float* __restrict__ x,
    const unsigned short* __restrict__ wbm,
    const float* __restrict__ mlpW,   // (4,16,112)
    const float* __restrict__ mlpB,   // (4,16)
    float* __restrict__ out)
{
    __shared__ __align__(16) char lds[49152];
    const int tid = threadIdx.x;
    const int lane = tid & 63, lr = lane & 15, lg = lane >> 4;
    const int wid = tid >> 6, wr = wid >> 1, wk = wid & 1;

    const unsigned u = blockIdx.x;                 // 0..2047
    const unsigned pid = (u & 7) * 256 + (u >> 3); // XCD-chunked
    const int kh = pid & 1;
    const int lt = (pid >> 1) & 15;
    const int b  = (pid >> 5) & 15;
    const int d  = (int)(pid >> 9);
    const int l0 = lt * 8;

    // ---- prefetch M(t=0) half-slab into regs (identity slot)
    short8 Mreg[4];
    {
        const unsigned short* src = wbm + 0 * 16384 + kh * 8192 + tid * 8;
        #pragma unroll
        for (int i = 0; i < 4; ++i)
            Mreg[i] = *reinterpret_cast<const short8*>(src + i * 2048);
    }

    // ---- stage X -> Xa[(n*16+c)][v] bf16, swizzled: byte = row*256 + (2v ^ ((row&7)<<4))
    {
        const int c = tid >> 4, vi = tid & 15;
        const float* xb = x + (size_t)b * 1048576 + d * 16384 + l0 + c * 65536;
        const int swz = (c & 7) << 4;
        #pragma unroll
        for (int vp = 0; vp < 4; ++vp) {
            const int v = (vp * 16 + vi) * 2;
            const float* p0 = xb + v * 128;
            const float4 a0 = *reinterpret_cast<const float4*>(p0);
            const float4 a1 = *reinterpret_cast<const float4*>(p0 + 4);
            const float4 b0 = *reinterpret_cast<const float4*>(p0 + 128);
            const float4 b1 = *reinterpret_cast<const float4*>(p0 + 132);
            const float av[8] = {a0.x, a0.y, a0.z, a0.w, a1.x, a1.y, a1.z, a1.w};
            const float bv[8] = {b0.x, b0.y, b0.z, b0.w, b1.x, b1.y, b1.z, b1.w};
            #pragma unroll
            for (int n = 0; n < 8; ++n) {
                const unsigned pk = (unsigned)f2bf(av[n]) | ((unsigned)f2bf(bv[n]) << 16);
                *reinterpret_cast<unsigned*>(lds + (n * 16 + c) * 256 + ((v * 2) ^ swz)) = pk;
            }
        }
    }

    // ---- W fragments (A-operand of phase B), zero-padded 8th t-slot
    short8 Wf[4];
    #pragma unroll
    for (int p = 0; p < 4; ++p) {
        short8 w;
        #pragma unroll
        for (int j = 0; j < 8; ++j) {
            const int tc = lg * 8 + j, t = 2 * p + (tc >> 4), c = tc & 15;
            const float wv = (t < 7) ? mlpW[d * 1792 + lr * 112 + t * 16 + c] : 0.f;
            w[j] = (short)f2bf(wv);
        }
        Wf[p] = w;
    }

    __syncthreads();   // Xa staged

    // ---- X A-fragments -> registers (Xa LDS is DEAD after this; Z overlays it)
    short8 Xf[4][4];
    {
        const int swz = (lr & 7) << 4;
        #pragma unroll
        for (int rti = 0; rti < 4; ++rti) {
            const int base = ((wr * 4 + rti) * 16 + lr) * 256;
            #pragma unroll
            for (int ks = 0; ks < 4; ++ks)
                Xf[rti][ks] = *reinterpret_cast<const short8*>(
                    lds + base + ((ks * 64 + lg * 16) ^ swz));
        }
    }
    // commit M0 regs -> Mbuf (disjoint region; vmcnt auto-drained)
    #pragma unroll
    for (int i = 0; i < 4; ++i)
        *reinterpret_cast<short8*>(lds + 32768 + (tid * 8 + i * 2048) * 2) = Mreg[i];

    __syncthreads();   // Mbuf ready, Xf reads drained

    const f32x4 zero4 = {0.f, 0.f, 0.f, 0.f};
    f32x4 Y[2][4];
    #pragma unroll
    for (int ni = 0; ni < 2; ++ni)
        #pragma unroll
        for (int kt = 0; kt < 4; ++kt) Y[ni][kt] = zero4;

    #pragma unroll
    for (int p = 0; p < 4; ++p) {
        #pragma unroll
        for (int tp = 0; tp < ((p < 3) ? 2 : 1); ++tp) {
            // prefetch next M half-slab into regs (hides under MFMA below)
            const int tnext = 2 * p + tp + 1;
            if (tnext <= 6) {
                const int slot = (tnext < 5) ? tnext : (5 + 2 * d + (tnext - 5));
                const unsigned short* src = wbm + slot * 16384 + kh * 8192 + tid * 8;
                #pragma unroll
                for (int i = 0; i < 4; ++i)
                    Mreg[i] = *reinterpret_cast<const short8*>(src + i * 2048);
            }
            // phase A: Z_t = X · M_t^T for this k-half
            f32x4 D[4][2];
            #pragma unroll
            for (int rti = 0; rti < 4; ++rti)
                #pragma unroll
                for (int j = 0; j < 2; ++j) D[rti][j] = zero4;
            #pragma unroll
            for (int ks = 0; ks < 4; ++ks) {
                short8 Bf[2];
                #pragma unroll
                for (int j = 0; j < 2; ++j) {
                    const int kp = (wk * 2 + j) * 16 + lr;
                    Bf[j] = *reinterpret_cast<const short8*>(
                        lds + 32768 + kp * 256 + ((ks * 64 + lg * 16) ^ ((kp & 7) << 4)));
                }
                #pragma unroll
                for (int rti = 0; rti < 4; ++rti)
                    #pragma unroll
                    for (int j = 0; j < 2; ++j)
                        D[rti][j] = __builtin_amdgcn_mfma_f32_16x16x32_bf16(
                            Xf[rti][ks], Bf[j], D[rti][j], 0, 0, 0);
            }
            // write Z[n][kp][tp][c] bf16 into region A (8B per store)
            #pragma unroll
            for (int rti = 0; rti < 4; ++rti) {
                #pragma unroll
                for (int j = 0; j < 2; ++j) {
                    const int n = wr * 4 + rti;
                    const int kp = (wk * 2 + j) * 16 + lr;
                    uint2 zz;
                    zz.x = (unsigned)f2bf(D[rti][j][0]) | ((unsigned)f2bf(D[rti][j][1]) << 16);
                    zz.y = (unsigned)f2bf(D[rti][j][2]) | ((unsigned)f2bf(D[rti][j][3]) << 16);
                    *reinterpret_cast<uint2*>(
                        lds + n * 4096 + ((kp * 64 + tp * 32 + lg * 8) ^ ((kp & 7) << 4))) = zz;
                }
            }
            __syncthreads();   // Z(tp) visible; Mbuf reads done
            if (tnext <= 6) {
                #pragma unroll
                for (int i = 0; i < 4; ++i)
                    *reinterpret_cast<short8*>(lds + 32768 + (tid * 8 + i * 2048) * 2) = Mreg[i];
                if (tp == 0 && p < 3) __syncthreads();   // Mbuf ready for tp=1
            }
        }
        // phase B: Y += W_pair · Z   (p=3: Z[tp=1] is stale but Wf[3] upper half = 0)
        #pragma unroll
        for (int ni = 0; ni < 2; ++ni) {
            #pragma unroll
            for (int ktl = 0; ktl < 4; ++ktl) {
                const int n = wid * 2 + ni;
                const int kp = ktl * 16 + lr;
                const short8 Bf = *reinterpret_cast<const short8*>(
                    lds + n * 4096 + ((kp * 64 + lg * 16) ^ ((kp & 7) << 4)));
                Y[ni][ktl] = __builtin_amdgcn_mfma_f32_16x16x32_bf16(
                    Wf[p], Bf, Y[ni][ktl], 0, 0, 0);
            }
        }
        if (p < 3) __syncthreads();   // Z region reused by next pair; Mbuf committed
    }

    // ---- store: out[b, o, d, k, l0+n], D rows are o = 4*lg + r
    f32x4 bias;
    #pragma unroll
    for (int r = 0; r < 4; ++r) bias[r] = mlpB[d * 16 + lg * 4 + r];
    float* ob = out + (size_t)b * 1048576 + d * 16384 + l0;
    #pragma unroll
    for (int ni = 0; ni < 2; ++ni) {
        const int n = wid * 2 + ni;
        #pragma unroll
        for (int ktl = 0; ktl < 4; ++ktl) {
            float* pp = ob + (kh * 64 + ktl * 16 + lr) * 128 + n;
            #pragma unroll
            for (int r = 0; r < 4; ++r)
                pp[(lg * 4 + r) * 65536] = Y[ni][ktl][r] + bias[r];
        }
    }
}

}  // namespace

extern "C" void kernel_launch(void* const* d_in, const int* in_sizes, int n_in,
                              void* d_out, int out_size, void* d_ws, size_t ws_size,
                              hipStream_t stream)
{
    const float* x    = (const float*)d_in[0];
    const float* sup  = (const float*)d_in[1];
    const float* nv1  = (const float*)d_in[2];
    const float* nv2  = (const float*)d_in[3];
    const float* impW = (const float*)d_in[4];
    const float* impB = (const float*)d_in[5];
    const float* mlpW = (const float*)d_in[6];
    const float* mlpB = (const float*)d_in[7];
    float* outp = (float*)d_out;

    float* fm = (float*)d_ws;                                        // 12 × 64KB fp32
    unsigned short* wbm = (unsigned short*)((char*)d_ws + 786432);   // 13 × 32KB bf16

    build_adj<<<6, 256, 0, stream>>>(sup, nv1, nv2, impW, impB, fm);
    square_adj<<<96, 256, 0, stream>>>(fm);
    cvt_mats<<<13, 256, 0, stream>>>(fm, wbm);
    fused_mfma<<<2048, 256, 0, stream>>>(x, wbm, mlpW, mlpB, outp);
}